// Round 8
// baseline (46.815 us; speedup 1.0000x reference)
//
#include <hip/hip_runtime.h>
#include <hip/hip_bf16.h>
#include <stdint.h>

#define NI 256
#define NT 256
#define NL 25
#define NE 128
#define NHW 49
#define NTL (NT*NL)   // 6400

#define WAVES 8            // waves (=images) per match WG
#define CH_T 16            // texts per chunk
#define CH_ROWS 400        // CH_T * NL
#define CH_BYTES 102400    // CH_ROWS * 256
#define NJ2 13             // 32-row text tiles per chunk (last is half)

typedef __attribute__((ext_vector_type(8))) short bf16x8;
typedef __attribute__((ext_vector_type(16))) float f32x16;

__device__ __forceinline__ short f2bf(float x) {
    __hip_bfloat16 h = __float2bfloat16(x);
    return *reinterpret_cast<short*>(&h);
}

__device__ __forceinline__ void gload_lds16(const void* g, void* l) {
    __builtin_amdgcn_global_load_lds(
        (const __attribute__((address_space(1))) unsigned int*)g,
        (__attribute__((address_space(3))) unsigned int*)l, 16, 0, 0);
}

// ---- Prep: blocks 0..399 build tf2 (bf16, XOR-swizzled 16B chunks);
//      blocks 400..655 build P2 (32x32x16 A-fragment lane order) ----
// tf2 row r: physical chunk c holds logical chunk c^(r&7).
// P2[i][frag=mt*8+ks][lane]: lane(r32=lane&31,hi=lane>>5) holds patch
// mt*32+r32, elems ks*16+hi*8 .. +8, zero for patch >= 49.
__global__ __launch_bounds__(256) void prep_kernel(
    const float* __restrict__ emb, const int* __restrict__ text,
    const float* __restrict__ img,
    __hip_bfloat16* __restrict__ tf2, __hip_bfloat16* __restrict__ P2)
{
    __shared__ float tile[NE * NHW];

    if (blockIdx.x < 400) {
        int idx = blockIdx.x * 256 + threadIdx.x;    // chunk id, 102400 total
        int r      = idx >> 4;
        int c_phys = idx & 15;
        int c_log  = c_phys ^ (r & 7);
        int tok = text[r];
        const float* src = emb + (size_t)tok * NE + c_log * 8;
        float4 a = *reinterpret_cast<const float4*>(src);
        float4 b = *reinterpret_cast<const float4*>(src + 4);
        bf16x8 o;
        o[0] = f2bf(a.x); o[1] = f2bf(a.y); o[2] = f2bf(a.z); o[3] = f2bf(a.w);
        o[4] = f2bf(b.x); o[5] = f2bf(b.y); o[6] = f2bf(b.z); o[7] = f2bf(b.w);
        *reinterpret_cast<bf16x8*>(tf2 + (size_t)r * NE + c_phys * 8) = o;
    } else {
        int i = blockIdx.x - 400;
        const float4* src4 = reinterpret_cast<const float4*>(img + (size_t)i * NE * NHW);
        float4* tile4 = reinterpret_cast<float4*>(tile);
        for (int idx = threadIdx.x; idx < NE * NHW / 4; idx += 256) tile4[idx] = src4[idx];
        __syncthreads();
        for (int idx = threadIdx.x; idx < 1024; idx += 256) {   // (frag, lane)
            int frag = idx >> 6, lane = idx & 63;
            int mt = frag >> 3, ks = frag & 7;
            int r32 = lane & 31, hi = lane >> 5;
            int p = mt * 32 + r32;
            bf16x8 o;
            #pragma unroll
            for (int j = 0; j < 8; j++) {
                int e = ks * 16 + hi * 8 + j;
                o[j] = (p < NHW) ? f2bf(tile[e * NHW + p]) : (short)0;
            }
            *reinterpret_cast<bf16x8*>(P2 + ((size_t)(i * 16 + frag) * 64 + lane) * 8) = o;
        }
    }
}

// ---- Match: fused 32x32x16-MFMA GEMM (swapped operands) + max + sum ----
// 512 WGs = 32 image-groups (8 images) x 16 text-chunks; wave = 1 image.
// D row = patch ((reg&3)+8*(reg>>2)+4*hi), D col = text (lane&31).
// Ring-3 8KB buffers (32 text rows each), counted vmcnt, raw s_barrier.
__global__ __launch_bounds__(512, 4) void match_kernel(
    const __hip_bfloat16* __restrict__ tf2,
    const __hip_bfloat16* __restrict__ P2,
    const int* __restrict__ text_length,
    const float* __restrict__ logit_scale,
    float* __restrict__ out)
{
    __shared__ __hip_bfloat16 Bbuf[3][32][NE];   // 3 ring slots x 8 KB (32 rows)
    __shared__ float vals[WAVES][NJ2][64];       // [wave][j2][lane] reduced max

    const int ig   = blockIdx.x & 31;    // image group (8 images)
    const int tq   = blockIdx.x >> 5;    // text chunk (16 texts = 400 rows)
    const int tid  = threadIdx.x;
    const int wave = tid >> 6;
    const int lane = tid & 63;
    const int r32  = lane & 31;
    const int hi   = lane >> 5;

    // pfrag: 16 coalesced 1KB loads from fragment-order P2, pinned resident
    const int img = ig * WAVES + wave;
    const bf16x8* p2 = reinterpret_cast<const bf16x8*>(P2) + (size_t)img * 16 * 64 + lane;
    bf16x8 pfrag[2][8];
    #pragma unroll
    for (int mt = 0; mt < 2; mt++)
        #pragma unroll
        for (int ks = 0; ks < 8; ks++)
            pfrag[mt][ks] = p2[(mt * 8 + ks) * 64];
    #pragma unroll
    for (int mt = 0; mt < 2; mt++)
        #pragma unroll
        for (int ks = 0; ks < 8; ks++)
            asm volatile("" : "+v"(pfrag[mt][ks]));

    const char* tsrc = (const char*)tf2 + (size_t)tq * CH_BYTES;
    char* lbase = (char*)&Bbuf[0][0][0];
    char* ldst  = lbase + wave * 1024;   // wave-uniform LDS dst (+lane*16 by HW)

    // stage j2-tile p (8 KB = 32 text rows): 512 threads x 16B, src clamped
    // (tile 12's rows 16-31 are dup/garbage; their D cols are never read).
    auto stage = [&](int p) {
        int off = p * 8192 + tid * 16;
        off = off > (CH_BYTES - 16) ? (CH_BYTES - 16) : off;
        gload_lds16(tsrc + off, ldst + (p % 3) * 8192);
    };

    // B-frag read offsets: row r32, logical chunk ks*2+hi, swizzled by r32&7
    int boffs[8];
    #pragma unroll
    for (int ks = 0; ks < 8; ks++)
        boffs[ks] = r32 * 256 + (((ks * 2 + hi) ^ (r32 & 7)) << 4);

    auto compute = [&](int slot, int j2) {
        const char* bb = lbase + slot * 8192;
        float vmax;
        #pragma unroll
        for (int mt = 0; mt < 2; mt++) {
            bf16x8 tfrag[8];
            #pragma unroll
            for (int ks = 0; ks < 8; ks++)
                tfrag[ks] = *reinterpret_cast<const bf16x8*>(bb + boffs[ks]);
            f32x16 acc = {};
            __builtin_amdgcn_s_setprio(1);
            #pragma unroll
            for (int ks = 0; ks < 8; ks++)
                acc = __builtin_amdgcn_mfma_f32_32x32x16_bf16(
                    pfrag[mt][ks], tfrag[ks], acc, 0, 0, 0);
            __builtin_amdgcn_s_setprio(0);
            if (mt == 0) {
                // patches 0..31: all 16 regs valid
                float a = fmaxf(fmaxf(acc[0], acc[1]),  fmaxf(acc[2], acc[3]));
                float b = fmaxf(fmaxf(acc[4], acc[5]),  fmaxf(acc[6], acc[7]));
                float c = fmaxf(fmaxf(acc[8], acc[9]),  fmaxf(acc[10], acc[11]));
                float d = fmaxf(fmaxf(acc[12], acc[13]), fmaxf(acc[14], acc[15]));
                vmax = fmaxf(fmaxf(a, b), fmaxf(c, d));
            } else {
                // patches 32..48: regs 0-7 (rows 0-15) + reg 8 iff hi==0 (patch 48)
                float a = fmaxf(fmaxf(acc[0], acc[1]), fmaxf(acc[2], acc[3]));
                float b = fmaxf(fmaxf(acc[4], acc[5]), fmaxf(acc[6], acc[7]));
                float c = (hi == 0) ? acc[8] : -3e38f;
                vmax = fmaxf(vmax, fmaxf(fmaxf(a, b), c));
            }
        }
        // combine the two half-row groups (lanes l, l+32 share text col)
        vmax = fmaxf(vmax, __shfl_xor(vmax, 32));
        vals[wave][j2][lane] = vmax;
    };

    stage(0);
    stage(1);
    // Phases p=0..12; per phase: vmcnt(1) (stage(p) landed, stage(p+1) may
    // fly) -> barrier -> issue stage(p+2) -> read frags + MFMA.
    #pragma unroll 1
    for (int p = 0; p < 11; p++) {
        asm volatile("s_waitcnt vmcnt(1)" ::: "memory");
        __builtin_amdgcn_s_barrier();
        asm volatile("" ::: "memory");
        stage(p + 2);
        compute(p % 3, p);
    }
    asm volatile("s_waitcnt vmcnt(1)" ::: "memory");   // P=11
    __builtin_amdgcn_s_barrier();
    asm volatile("" ::: "memory");
    compute(11 % 3, 11);
    asm volatile("s_waitcnt vmcnt(0)" ::: "memory");   // P=12 (half tile)
    __builtin_amdgcn_s_barrier();
    asm volatile("" ::: "memory");
    compute(12 % 3, 12);
    __syncthreads();

    // Epilogue: length-25 sum + scale; 128 outputs per WG, both layouts.
    if (tid < WAVES * CH_T) {
        int g  = tid >> 4;
        int tl = tid & 15;
        float s = 0.f;
        #pragma unroll
        for (int l = 0; l < 25; l++) {
            int row = tl * 25 + l;          // text row within chunk, 0..399
            s += vals[g][row >> 5][row & 31];
        }
        int t = tq * CH_T + tl;
        int i = ig * WAVES + g;
        float val = s / (float)text_length[t] * expf(logit_scale[0]);
        out[(size_t)i * NT + t] = val;                      // logits_per_image [I,T]
        out[(size_t)NI * NT + (size_t)t * NI + i] = val;    // logits_per_text  [T,I]
    }
}

extern "C" void kernel_launch(void* const* d_in, const int* in_sizes, int n_in,
                              void* d_out, int out_size, void* d_ws, size_t ws_size,
                              hipStream_t stream)
{
    const float* img  = (const float*)d_in[0];   // [256,128,7,7]
    const float* emb  = (const float*)d_in[1];   // [10000,128]
    const float* ls   = (const float*)d_in[2];   // scalar
    const int*   text = (const int*)d_in[3];     // [256,25]
    const int*   tlen = (const int*)d_in[4];     // [256]
    float* out = (float*)d_out;

    __hip_bfloat16* tf2 = (__hip_bfloat16*)d_ws;                                  // 1,638,400 B
    __hip_bfloat16* P2  = (__hip_bfloat16*)((char*)d_ws + (size_t)NTL * NE * 2);  // 4,194,304 B

    prep_kernel<<<400 + NI, 256, 0, stream>>>(emb, text, img, tf2, P2);
    match_kernel<<<512, 512, 0, stream>>>(tf2, P2, tlen, ls, out);
}

// Round 9
// 34.151 us; speedup vs baseline: 1.3708x; 1.3708x over previous
//
#include <hip/hip_runtime.h>
#include <hip/hip_bf16.h>
#include <stdint.h>

#define NI 256
#define NT 256
#define NL 25
#define NE 128
#define NHW 49
#define NTL (NT*NL)   // 6400

#define WAVES 8            // waves (=images) per match WG
#define CH_T 16            // texts per chunk
#define CH_TILES 25        // 16-row B tiles per chunk

typedef __attribute__((ext_vector_type(8))) short bf16x8;
typedef __attribute__((ext_vector_type(4))) float f32x4;

__device__ __forceinline__ short f2bf(float x) {
    __hip_bfloat16 h = __float2bfloat16(x);
    return *reinterpret_cast<short*>(&h);
}

// ---- Prep ----
// blocks 0..399: tf3 in B-fragment order: chunk idx=(j*4+k)*64+lane holds
//   TF[row=j*16+(lane&15)][k*32+(lane>>4)*8 .. +8] as bf16x8.
// blocks 400..655: P2 in A-fragment order (16x16): P2[i][m*4+k][lane] holds
//   patch m*16+(lane&15), elems k*32+(lane>>4)*8 .. +8, zero for patch>=49.
__global__ __launch_bounds__(256) void prep_kernel(
    const float* __restrict__ emb, const int* __restrict__ text,
    const float* __restrict__ img,
    __hip_bfloat16* __restrict__ tf3, __hip_bfloat16* __restrict__ P2)
{
    __shared__ float tile[NE * NHW];

    if (blockIdx.x < 400) {
        int idx  = blockIdx.x * 256 + threadIdx.x;   // 16B chunk id, 102400 total
        int lane = idx & 63;
        int k    = (idx >> 6) & 3;
        int j    = idx >> 8;                         // 0..399
        int lr = lane & 15, lhi = lane >> 4;
        int row = j * 16 + lr;
        int tok = text[row];
        const float* src = emb + (size_t)tok * NE + k * 32 + lhi * 8;
        float4 a = *reinterpret_cast<const float4*>(src);
        float4 b = *reinterpret_cast<const float4*>(src + 4);
        bf16x8 o;
        o[0] = f2bf(a.x); o[1] = f2bf(a.y); o[2] = f2bf(a.z); o[3] = f2bf(a.w);
        o[4] = f2bf(b.x); o[5] = f2bf(b.y); o[6] = f2bf(b.z); o[7] = f2bf(b.w);
        *reinterpret_cast<bf16x8*>(tf3 + (size_t)idx * 8) = o;
    } else {
        int i = blockIdx.x - 400;
        const float4* src4 = reinterpret_cast<const float4*>(img + (size_t)i * NE * NHW);
        float4* tile4 = reinterpret_cast<float4*>(tile);
        for (int idx = threadIdx.x; idx < NE * NHW / 4; idx += 256) tile4[idx] = src4[idx];
        __syncthreads();
        for (int idx = threadIdx.x; idx < 1024; idx += 256) {   // (mk, lane)
            int mk = idx >> 6, lane = idx & 63;
            int m = mk >> 2, k = mk & 3;
            int lr = lane & 15, lhi = lane >> 4;
            int p = m * 16 + lr;
            bf16x8 o;
            #pragma unroll
            for (int j = 0; j < 8; j++) {
                int e = k * 32 + lhi * 8 + j;
                o[j] = (p < NHW) ? f2bf(tile[e * NHW + p]) : (short)0;
            }
            *reinterpret_cast<bf16x8*>(P2 + ((size_t)(i * 16 + mk) * 64 + lane) * 8) = o;
        }
    }
}

// ---- Match: register-resident MFMA GEMM, B-fragments streamed from L1/L2 ----
// 512 WGs = 32 image-groups (8 images) x 16 text-chunks; wave = 1 image.
// No LDS staging / barriers in the loop: each B-fragment is one coalesced
// 1KB load from fragment-order tf3 (shared across the WG's 8 waves -> L1).
// Per-lane 16-patch max goes to vals; epilogue maxes the 4 lane-groups.
__global__ __launch_bounds__(512, 4) void match_kernel(
    const __hip_bfloat16* __restrict__ tf3,
    const __hip_bfloat16* __restrict__ P2,
    const int* __restrict__ text_length,
    const float* __restrict__ logit_scale,
    float* __restrict__ out)
{
    __shared__ float vals[WAVES][CH_TILES][64];   // per-lane 16-patch max

    const int ig   = blockIdx.x & 31;    // image group (8 images)
    const int tq   = blockIdx.x >> 5;    // text chunk (16 texts = 25 tiles)
    const int tid  = threadIdx.x;
    const int wave = tid >> 6;
    const int lane = tid & 63;
    const int lhi  = lane >> 4;

    // pfrag: 16 coalesced 1KB loads from fragment-order P2, pinned resident
    const int img = ig * WAVES + wave;
    const bf16x8* p2 = reinterpret_cast<const bf16x8*>(P2) + (size_t)img * 16 * 64 + lane;
    bf16x8 pfrag[4][4];
    #pragma unroll
    for (int m = 0; m < 4; m++)
        #pragma unroll
        for (int k = 0; k < 4; k++)
            pfrag[m][k] = p2[(m * 4 + k) * 64];
    #pragma unroll
    for (int m = 0; m < 4; m++)
        #pragma unroll
        for (int k = 0; k < 4; k++)
            asm volatile("" : "+v"(pfrag[m][k]));

    // B-fragment stream base: tile j at +j*4096, k at +k*1024, lane*16
    const char* tb = (const char*)tf3 + (size_t)tq * CH_TILES * 4096 + lane * 16;

    auto loadT = [&](bf16x8* T, int j) {
        #pragma unroll
        for (int k = 0; k < 4; k++)
            T[k] = *reinterpret_cast<const bf16x8*>(tb + j * 4096 + k * 1024);
    };

    // two m-halves serially (acc = 8 regs) to stay under the 128-VGPR cap
    auto compute = [&](const bf16x8* T, int j) {
        float vmax;
        #pragma unroll
        for (int mh = 0; mh < 2; mh++) {
            f32x4 acc0 = {}, acc1 = {};
            #pragma unroll
            for (int k = 0; k < 4; k++) {
                acc0 = __builtin_amdgcn_mfma_f32_16x16x32_bf16(
                    pfrag[mh * 2][k], T[k], acc0, 0, 0, 0);
                acc1 = __builtin_amdgcn_mfma_f32_16x16x32_bf16(
                    pfrag[mh * 2 + 1][k], T[k], acc1, 0, 0, 0);
            }
            if (mh == 0) {
                float a = fmaxf(fmaxf(acc0[0], acc0[1]), fmaxf(acc0[2], acc0[3]));
                float b = fmaxf(fmaxf(acc1[0], acc1[1]), fmaxf(acc1[2], acc1[3]));
                vmax = fmaxf(a, b);
            } else {
                // m-tile 2 (patches 32..47) all valid; m-tile 3: only patch 48
                float c = fmaxf(fmaxf(acc0[0], acc0[1]), fmaxf(acc0[2], acc0[3]));
                float d = (lhi == 0) ? acc1[0] : -3e38f;
                vmax = fmaxf(vmax, fmaxf(c, d));
            }
        }
        vals[wave][j][lane] = vmax;
    };

    bf16x8 A[4], B[4];
    loadT(A, 0);
    #pragma unroll 1
    for (int jj = 0; jj < 12; jj++) {
        loadT(B, 2 * jj + 1);
        compute(A, 2 * jj);
        loadT(A, 2 * jj + 2);
        compute(B, 2 * jj + 1);
    }
    compute(A, 24);
    __syncthreads();

    // Epilogue: max over 4 lane-groups + length-25 sum + scale; 128 outputs.
    if (tid < WAVES * CH_T) {
        int g  = tid >> 4;
        int tl = tid & 15;
        float s = 0.f;
        #pragma unroll
        for (int l = 0; l < 25; l++) {
            int row = tl * 25 + l;          // text row within chunk, 0..399
            int j = row >> 4;
            int r = row & 15;
            float m0 = fmaxf(vals[g][j][r],      vals[g][j][r + 16]);
            float m1 = fmaxf(vals[g][j][r + 32], vals[g][j][r + 48]);
            s += fmaxf(m0, m1);
        }
        int t = tq * CH_T + tl;
        int i = ig * WAVES + g;
        float val = s / (float)text_length[t] * expf(logit_scale[0]);
        out[(size_t)i * NT + t] = val;                      // logits_per_image [I,T]
        out[(size_t)NI * NT + (size_t)t * NI + i] = val;    // logits_per_text  [T,I]
    }
}

extern "C" void kernel_launch(void* const* d_in, const int* in_sizes, int n_in,
                              void* d_out, int out_size, void* d_ws, size_t ws_size,
                              hipStream_t stream)
{
    const float* img  = (const float*)d_in[0];   // [256,128,7,7]
    const float* emb  = (const float*)d_in[1];   // [10000,128]
    const float* ls   = (const float*)d_in[2];   // scalar
    const int*   text = (const int*)d_in[3];     // [256,25]
    const int*   tlen = (const int*)d_in[4];     // [256]
    float* out = (float*)d_out;

    __hip_bfloat16* tf3 = (__hip_bfloat16*)d_ws;                                  // 1,638,400 B
    __hip_bfloat16* P2  = (__hip_bfloat16*)((char*)d_ws + (size_t)NTL * NE * 2);  // 4,194,304 B

    prep_kernel<<<400 + NI, 256, 0, stream>>>(emb, text, img, tf3, P2);
    match_kernel<<<512, 512, 0, stream>>>(tf3, P2, tlen, ls, out);
}